// Round 19
// baseline (443.474 us; speedup 1.0000x reference)
//
#include <hip/hip_runtime.h>
#include <hip/hip_bf16.h>

typedef __bf16 bf16;
typedef __bf16 bf16x8 __attribute__((ext_vector_type(8)));
typedef float f32x4 __attribute__((ext_vector_type(4)));
typedef unsigned int u32x2 __attribute__((ext_vector_type(2)));
typedef unsigned int u32x4 __attribute__((ext_vector_type(4)));

#define DEVI static __device__ __forceinline__

static constexpr int Bn = 4, Cc = 192, Hh = 256, Wd = 256;
static constexpr int NHd = 6, HD = 32;
static constexpr int Mtot = Bn * Hh * Wd;          // 262144 pixels
static constexpr float EPSv = 1e-5f;
static constexpr float SCQ = 0.2550629072427404f;  // hd^-0.5 * log2(e), folded into Q

DEVI f32x4 mfma16(bf16x8 a, bf16x8 b, f32x4 c) {
    return __builtin_amdgcn_mfma_f32_16x16x32_bf16(a, b, c, 0, 0, 0);
}

DEVI f32x4 mfma16f8(long long a, long long b, f32x4 c) {
    return __builtin_amdgcn_mfma_f32_16x16x32_fp8_fp8(a, b, c, 0, 0, 0);
}

DEVI unsigned cvtpk_bf16(float lo, float hi) {
    unsigned r;
    asm("v_cvt_pk_bf16_f32 %0, %1, %2" : "=v"(r) : "v"(lo), "v"(hi));
    return r;
}

template <bool HIGH>
DEVI unsigned cvtpk_fp8(float lo, float hi, unsigned old) {
    return (unsigned)__builtin_amdgcn_cvt_pk_fp8_f32(lo, hi, (int)old, HIGH);
}

// ---------------------------------------------------------------- K0: weights
// WT576[n][k]: rows 0..191 = Wq^T * SCQ, rows 192..575 = Wkv^T.  WoT = Wo^T.
__global__ __launch_bounds__(256) void k_prep(const float* Wq, const float* Wkv,
                                              const float* Wo, bf16* WT, bf16* WoT) {
    int idx = blockIdx.x * 256 + threadIdx.x;
    if (idx < 576 * 192) {
        int n = idx / 192, k = idx % 192;
        float v = (n < 192) ? Wq[k * 192 + n] * SCQ : Wkv[k * 384 + (n - 192)];
        WT[idx] = (bf16)v;
    } else if (idx < 576 * 192 + 192 * 192) {
        int j = idx - 576 * 192;
        int n = j / 192, k = j % 192;
        WoT[j] = (bf16)Wo[k * 192 + n];
    }
}

// ---------------------------------------------------------------- K1: fused LN + QKV projection
// PERSISTENT 4-tile blocks with cross-tile x prefetch: while tile t's GEMM
// runs, tile t+1's 48 x-loads are in flight (issued before the MFMA block,
// consumed after). Exposed HBM latency 4096x -> 1024x. Outputs fp8.
__global__ __launch_bounds__(256) void k_lnqkv(const float* __restrict__ x,
                                               const float* __restrict__ gamma,
                                               const float* __restrict__ beta,
                                               const bf16* __restrict__ WT,
                                               const float* __restrict__ bq,
                                               const float* __restrict__ bkv,
                                               unsigned char* __restrict__ QKV8) {
    constexpr int AS = 200;                       // A-tile stride
    __shared__ __align__(16) bf16 A[64 * AS];
    __shared__ float red[2][4][64];
    __shared__ float sg[Cc], sbv[Cc];

    int tid = threadIdx.x;
    int q = tid >> 6, p = tid & 63;
    if (tid < Cc) { sg[tid] = gamma[tid]; sbv[tid] = beta[tid]; }
    int lane = tid & 63, l15 = lane & 15, g = lane >> 4;
    const bf16* Wbase = WT + (size_t)(q * 144 + l15) * Cc + g * 8;

    int base0 = blockIdx.x * 256;                 // 4 tiles of 64 pixels
    float xv[48];
    {   // load tile 0
        int b = base0 >> 16, hw = base0 & 65535, h = hw >> 8, w0 = hw & 255;
        const float* xb = x + ((size_t)(b * Cc + q * 48) * Hh + h) * Wd + w0 + p;
#pragma unroll
        for (int i = 0; i < 48; ++i) xv[i] = xb[(size_t)i * Hh * Wd];
    }

#pragma unroll 1
    for (int t = 0; t < 4; ++t) {
        int base = base0 + t * 64;
        // stats for the tile currently in xv
        float s = 0.f, s2 = 0.f;
#pragma unroll
        for (int i = 0; i < 48; ++i) { s += xv[i]; s2 += xv[i] * xv[i]; }
        red[0][q][p] = s; red[1][q][p] = s2;
        __syncthreads();   // red visible; all waves done reading A (prev GEMM)
        float mu = (red[0][0][p] + red[0][1][p] + red[0][2][p] + red[0][3][p]) * (1.f / 192.f);
        float m2 = (red[1][0][p] + red[1][1][p] + red[1][2][p] + red[1][3][p]) * (1.f / 192.f);
        float rs = rsqrtf(m2 - mu * mu + EPSv);
        // normalize from registers, write A once (frees xv)
#pragma unroll
        for (int i0 = 0; i0 < 48; i0 += 8) {
            bf16x8 o;
#pragma unroll
            for (int j = 0; j < 8; ++j) {
                int c = q * 48 + i0 + j;
                o[j] = (bf16)((xv[i0 + j] - mu) * rs * sg[c] + sbv[c]);
            }
            *(bf16x8*)&A[p * AS + q * 48 + i0] = o;
        }
        __syncthreads();   // A visible
        // prefetch next tile's x: loads issue now, drain under the GEMM below
        if (t < 3) {
            int nb2 = base0 + (t + 1) * 64;
            int b = nb2 >> 16, hw = nb2 & 65535, h = hw >> 8, w0 = hw & 255;
            const float* xb = x + ((size_t)(b * Cc + q * 48) * Hh + h) * Wd + w0 + p;
#pragma unroll
            for (int i = 0; i < 48; ++i) xv[i] = xb[(size_t)i * Hh * Wd];
        }
        // GEMM: 4 waves x 144 cols; nt streamed OUTER (W read once), mt inner.
#pragma unroll 1
        for (int nt = 0; nt < 9; ++nt) {
            f32x4 acc[4] = {};
            const bf16* wp = Wbase + (size_t)nt * 16 * Cc;
#pragma unroll
            for (int kk = 0; kk < 6; ++kk) {
                bf16x8 wb = *(const bf16x8*)(wp + kk * 32);
#pragma unroll
                for (int mt = 0; mt < 4; ++mt) {
                    bf16x8 a = *(bf16x8*)&A[(mt * 16 + l15) * AS + kk * 32 + g * 8];
                    acc[mt] = mfma16(wb, a, acc[mt]);   // D[n][pix]
                }
            }
            int n0 = q * 144 + nt * 16 + g * 4;     // 4-group never crosses plane
            const float* bsrc = (n0 < 192) ? (bq + n0) : (bkv + n0 - 192);
            f32x4 b4 = *(const f32x4*)bsrc;
            if (n0 < 192) b4 *= SCQ;                // Q bias pre-scaled like Wq
            unsigned char* outp = QKV8 + (size_t)(n0 >> 5) * Mtot * HD + (n0 & 31);
#pragma unroll
            for (int mt = 0; mt < 4; ++mt) {
                unsigned pk = 0;
                pk = cvtpk_fp8<false>(acc[mt][0] + b4[0], acc[mt][1] + b4[1], pk);
                pk = cvtpk_fp8<true>(acc[mt][2] + b4[2], acc[mt][3] + b4[3], pk);
                *(unsigned*)(outp + (size_t)(base + mt * 16 + l15) * HD) = pk;
            }
        }
    }
}

// ---------------------------------------------------------------- K2: attention
// 2 waves x 128 threads per (head, window); q-tiles A/B share the K stream.
// FULL fp8 pipeline: Q,K,V,P all fp8 (QK^T and PV via mfma16f8). In-register
// P via shuffles; LDS = V^T only. No row-max (pre-scaled Q).
__global__ __launch_bounds__(128) void k_attn(const unsigned char* __restrict__ QKV8,
                                              const float* __restrict__ bkv,
                                              bf16* __restrict__ O) {
    constexpr int VS = 264;                        // VT row stride BYTES
    int bid = blockIdx.x;
    bid = (bid & 7) * 3072 + (bid >> 3);          // chunked XCD swizzle (24576 = 8*3072)
    int head = bid >> 12;                          // /4096
    int win = bid & 4095;
    int b = win >> 10, wloc = win & 1023;
    int h0 = ((wloc >> 5) << 3), w0 = ((wloc & 31) << 3);
    bool interior = (h0 != 0) && (h0 != Hh - 8) && (w0 != 0) && (w0 != Wd - 8);

    int tid = threadIdx.x, wave = tid >> 6, lane = tid & 63;
    int l15 = lane & 15, g = lane >> 4;

    const unsigned char* Qh = QKV8 + (size_t)head * Mtot * HD;
    const unsigned char* Kh = QKV8 + (size_t)(6 + head) * Mtot * HD;
    const unsigned char* Vh = QKV8 + (size_t)(12 + head) * Mtot * HD;
    bf16* Oh = O + (size_t)head * Mtot * HD;
    long long p00 = (long long)(b * Hh + h0 - 4) * Wd + (w0 - 4);

    __shared__ __align__(16) unsigned char VT8[32 * VS];  // fp8 V^T [d][kv]

    // ---- stage V^T (two kv rows per thread), fp8
#pragma unroll
    for (int rr = 0; rr < 2; ++rr) {
        int r = tid + rr * 128;
        unsigned wv[8];
        if (interior) {
            const unsigned char* vr = Vh + (p00 + (r >> 4) * Wd + (r & 15)) * HD;
            u32x4 a0 = *(const u32x4*)(vr);
            u32x4 a1 = *(const u32x4*)(vr + 16);
#pragma unroll
            for (int w = 0; w < 4; ++w) { wv[w] = a0[w]; wv[w + 4] = a1[w]; }
        } else {
            int ph = h0 - 4 + (r >> 4), pw = w0 - 4 + (r & 15);
            bool ok = ((unsigned)ph < (unsigned)Hh) && ((unsigned)pw < (unsigned)Wd);
            long long pix = ok ? ((long long)(b * Hh + ph) * Wd + pw) : 0;
            const unsigned char* vr = Vh + pix * HD;
            u32x4 a0 = *(const u32x4*)(vr);
            u32x4 a1 = *(const u32x4*)(vr + 16);
            const float* vb = bkv + Cc + head * HD;
#pragma unroll
            for (int w = 0; w < 8; ++w) {
                unsigned bw = 0;
                bw = cvtpk_fp8<false>(vb[4 * w], vb[4 * w + 1], bw);
                bw = cvtpk_fp8<true>(vb[4 * w + 2], vb[4 * w + 3], bw);
                unsigned lw = (w < 4) ? a0[w] : a1[w - 4];
                wv[w] = ok ? lw : bw;
            }
        }
#pragma unroll
        for (int w = 0; w < 8; ++w) {
            unsigned word = wv[w];
            VT8[(4 * w + 0) * VS + r] = (unsigned char)(word);
            VT8[(4 * w + 1) * VS + r] = (unsigned char)(word >> 8);
            VT8[(4 * w + 2) * VS + r] = (unsigned char)(word >> 16);
            VT8[(4 * w + 3) * VS + r] = (unsigned char)(word >> 24);
        }
    }

    // ---- Q fragments (fp8, 8B each) for the wave's two q-tiles
    int qrA = wave * 32 + l15;
    int qrB = qrA + 16;
    size_t qpixA = (size_t)(b * Hh + h0 + (qrA >> 3)) * Wd + w0 + (qrA & 7);
    size_t qpixB = (size_t)(b * Hh + h0 + (qrB >> 3)) * Wd + w0 + (qrB & 7);
    long long aqA = *(const long long*)(Qh + qpixA * HD + g * 8);
    long long aqB = *(const long long*)(Qh + qpixB * HD + g * 8);
    __syncthreads();

    // ---- S^T = K @ Q^T (fp8) fused with exp/pack, 4 chunks of 4 kv-tiles.
    const f32x4 z = {0.f, 0.f, 0.f, 0.f};
    const unsigned char* kp = Kh + (p00 + l15) * HD + g * 8;
    float sa0 = 0.f, sa1 = 0.f, sa2 = 0.f, sa3 = 0.f;
    float sb0 = 0.f, sb1 = 0.f, sb2 = 0.f, sb3 = 0.f;
    unsigned pkA[16], pkB[16];
    long long kb = 0;
    bool colok = true;
    if (!interior) {
        unsigned kb0 = 0, kb1 = 0;
        const float* kbp = bkv + head * HD + g * 8;
        kb0 = cvtpk_fp8<false>(kbp[0], kbp[1], kb0);
        kb0 = cvtpk_fp8<true>(kbp[2], kbp[3], kb0);
        kb1 = cvtpk_fp8<false>(kbp[4], kbp[5], kb1);
        kb1 = cvtpk_fp8<true>(kbp[6], kbp[7], kb1);
        kb = (long long)(((unsigned long long)kb1 << 32) | kb0);
        colok = ((unsigned)(w0 - 4 + l15) < (unsigned)Wd);
    }
#pragma unroll 1
    for (int c = 0; c < 4; ++c) {
        f32x4 sA[4], sB[4];
        __builtin_amdgcn_s_setprio(1);
        if (interior) {
#pragma unroll
            for (int u = 0; u < 4; ++u) {
                long long kf = *(const long long*)(kp + (size_t)(c * 4 + u) * Wd * HD);
                sA[u] = mfma16f8(kf, aqA, z);
                sB[u] = mfma16f8(kf, aqB, z);
            }
        } else {
#pragma unroll
            for (int u = 0; u < 4; ++u) {
                int t = c * 4 + u;
                int ph = h0 - 4 + t;              // wave-uniform
                long long kf;
                if ((unsigned)ph < (unsigned)Hh) {
                    kf = *(const long long*)(kp + (size_t)t * Wd * HD);
                    kf = colok ? kf : kb;
                } else {
                    kf = kb;
                }
                sA[u] = mfma16f8(kf, aqA, z);
                sB[u] = mfma16f8(kf, aqB, z);
            }
        }
        __builtin_amdgcn_s_setprio(0);
#pragma unroll
        for (int u = 0; u < 4; ++u) {
            float a0 = __builtin_amdgcn_exp2f(sA[u][0]);
            float a1 = __builtin_amdgcn_exp2f(sA[u][1]);
            float a2 = __builtin_amdgcn_exp2f(sA[u][2]);
            float a3 = __builtin_amdgcn_exp2f(sA[u][3]);
            sa0 += a0; sa1 += a1; sa2 += a2; sa3 += a3;
            unsigned wA = 0;
            wA = cvtpk_fp8<false>(a0, a1, wA);
            wA = cvtpk_fp8<true>(a2, a3, wA);
            pkA[c * 4 + u] = wA;
            float b0 = __builtin_amdgcn_exp2f(sB[u][0]);
            float b1 = __builtin_amdgcn_exp2f(sB[u][1]);
            float b2 = __builtin_amdgcn_exp2f(sB[u][2]);
            float b3 = __builtin_amdgcn_exp2f(sB[u][3]);
            sb0 += b0; sb1 += b1; sb2 += b2; sb3 += b3;
            unsigned wB = 0;
            wB = cvtpk_fp8<false>(b0, b1, wB);
            wB = cvtpk_fp8<true>(b2, b3, wB);
            pkB[c * 4 + u] = wB;
        }
    }
    float sumA = (sa0 + sa1) + (sa2 + sa3);
    sumA += __shfl_xor(sumA, 16);
    sumA += __shfl_xor(sumA, 32);
    float invA = __builtin_amdgcn_rcpf(sumA);
    float sumB = (sb0 + sb1) + (sb2 + sb3);
    sumB += __shfl_xor(sumB, 16);
    sumB += __shfl_xor(sumB, 32);
    float invB = __builtin_amdgcn_rcpf(sumB);

    // ---- O = P @ V in fp8 per q-tile; MACRO keeps pkA/pkB register-resident
    int srcA = l15 | ((2 * (g & 1)) << 4);
    int srcB = srcA + 16;
    bool ghi = (g >> 1) != 0;
#define PV_EPILOGUE(PK, INV, JT)                                                        \
    {                                                                                   \
        f32x4 o0 = z, o1 = z;                                                           \
        _Pragma("unroll")                                                               \
        for (int kk = 0; kk < 8; ++kk) {                                                \
            unsigned s0 = __shfl(PK[2 * kk], srcA);                                     \
            unsigned s1 = __shfl(PK[2 * kk + 1], srcA);                                 \
            unsigned s2 = __shfl(PK[2 * kk], srcB);                                     \
            unsigned s3 = __shfl(PK[2 * kk + 1], srcB);                                 \
            unsigned lo = ghi ? s1 : s0;                                                \
            unsigned hi = ghi ? s3 : s2;                                                \
            long long ap = (long long)(((unsigned long long)hi << 32) | lo);            \
            long long bv0 = *(const long long*)&VT8[l15 * VS + kk * 32 + g * 8];        \
            long long bv1 = *(const long long*)&VT8[(16 + l15) * VS + kk * 32 + g * 8]; \
            __builtin_amdgcn_s_setprio(1);                                              \
            o0 = mfma16f8(ap, bv0, o0);                                                 \
            o1 = mfma16f8(ap, bv1, o1);                                                 \
            __builtin_amdgcn_s_setprio(0);                                              \
        }                                                                               \
        float invr[4];                                                                  \
        _Pragma("unroll")                                                               \
        for (int r = 0; r < 4; ++r)                                                     \
            invr[r] = __shfl(INV, (lane & 48) | (g * 4 + r));                           \
        _Pragma("unroll")                                                               \
        for (int r = 0; r < 4; ++r) {                                                   \
            int row = wave * 32 + JT * 16 + g * 4 + r;                                  \
            size_t pix = (size_t)(b * Hh + h0 + (row >> 3)) * Wd + w0 + (row & 7);      \
            Oh[pix * HD + l15] = (bf16)(o0[r] * invr[r]);                               \
            Oh[pix * HD + 16 + l15] = (bf16)(o1[r] * invr[r]);                          \
        }                                                                               \
    }
    PV_EPILOGUE(pkA, invA, 0)
    PV_EPILOGUE(pkB, invB, 1)
#undef PV_EPILOGUE
}

// ---------------------------------------------------------------- K3: O-proj + residual (BHWC->BCHW)
__global__ __launch_bounds__(256) void k_out(const bf16* __restrict__ AO,
                                             const bf16* __restrict__ WoT,
                                             const float* __restrict__ bo,
                                             const float* __restrict__ x,
                                             float* __restrict__ out) {
    int row0 = blockIdx.x * 64;
    int tid = threadIdx.x, wave = tid >> 6, lane = tid & 63;
    int l15 = lane & 15, g = lane >> 4;
    int nb = wave * 48;
    f32x4 acc[4][3] = {};
    const bf16* Arow[4];
#pragma unroll
    for (int mt = 0; mt < 4; ++mt) Arow[mt] = AO + (size_t)(row0 + mt * 16 + l15) * HD + g * 8;
    const bf16* Wrow[3];
#pragma unroll
    for (int nt = 0; nt < 3; ++nt) Wrow[nt] = WoT + (size_t)(nb + nt * 16 + l15) * Cc + g * 8;
#pragma unroll
    for (int kk = 0; kk < 6; ++kk) {
        bf16x8 a[4];
#pragma unroll
        for (int mt = 0; mt < 4; ++mt)
            a[mt] = *(const bf16x8*)(Arow[mt] + (size_t)kk * Mtot * HD);
#pragma unroll
        for (int nt = 0; nt < 3; ++nt) {
            bf16x8 bb = *(const bf16x8*)(Wrow[nt] + kk * 32);
#pragma unroll
            for (int mt = 0; mt < 4; ++mt) acc[mt][nt] = mfma16(a[mt], bb, acc[mt][nt]);
        }
    }
    __shared__ float st[192 * 65];
#pragma unroll
    for (int nt = 0; nt < 3; ++nt) {
        float bval = bo[nb + nt * 16 + l15];
#pragma unroll
        for (int mt = 0; mt < 4; ++mt)
#pragma unroll
            for (int r = 0; r < 4; ++r) {
                int ccol = nb + nt * 16 + l15;
                int px = mt * 16 + g * 4 + r;
                st[ccol * 65 + px] = acc[mt][nt][r] + bval;
            }
    }
    __syncthreads();
    int bb2 = row0 / (Hh * Wd);
    int rem = row0 % (Hh * Wd);
    int h = rem / Wd, wstart = rem % Wd;
    for (int idx = tid; idx < 192 * 64; idx += 256) {
        int cc = idx >> 6, px = idx & 63;
        size_t ga = ((size_t)(bb2 * Cc + cc) * Hh + h) * Wd + wstart + px;
        out[ga] = st[cc * 65 + px] + x[ga];
    }
}

// ---------------------------------------------------------------- launch
extern "C" void kernel_launch(void* const* d_in, const int* in_sizes, int n_in,
                              void* d_out, int out_size, void* d_ws, size_t ws_size,
                              hipStream_t stream) {
    const float* x     = (const float*)d_in[0];
    const float* gamma = (const float*)d_in[1];
    const float* beta  = (const float*)d_in[2];
    const float* Wq    = (const float*)d_in[3];
    const float* bq    = (const float*)d_in[4];
    const float* Wkv   = (const float*)d_in[5];
    const float* bkv   = (const float*)d_in[6];
    const float* Wo    = (const float*)d_in[7];
    const float* bo    = (const float*)d_in[8];
    float* out = (float*)d_out;

    char* ws = (char*)d_ws;
    constexpr size_t P8  = (size_t)Mtot * HD;               // 8388608 B (fp8 plane)
    constexpr size_t QKV8SZ = 18 * P8;                      // 150994944
    unsigned char* QKV8 = (unsigned char*)(ws);
    bf16*          AO   = (bf16*)(ws + QKV8SZ);             // 6 bf16 planes = 100663296
    bf16*          WT   = (bf16*)(ws + QKV8SZ + 6 * P8 * 2);
    bf16*          WoT  = (bf16*)(ws + QKV8SZ + 6 * P8 * 2 + 221184);

    k_prep<<<576, 256, 0, stream>>>(Wq, Wkv, Wo, WT, WoT);
    k_lnqkv<<<Mtot / 256, 256, 0, stream>>>(x, gamma, beta, WT, bq, bkv, QKV8);
    k_attn<<<4096 * NHd, 128, 0, stream>>>(QKV8, bkv, AO);
    k_out<<<Mtot / 64, 256, 0, stream>>>(AO, WoT, bo, x, out);
}

// Round 20
// 403.456 us; speedup vs baseline: 1.0992x; 1.0992x over previous
//
#include <hip/hip_runtime.h>
#include <hip/hip_bf16.h>

typedef __bf16 bf16;
typedef __bf16 bf16x8 __attribute__((ext_vector_type(8)));
typedef float f32x4 __attribute__((ext_vector_type(4)));
typedef unsigned int u32x2 __attribute__((ext_vector_type(2)));
typedef unsigned int u32x4 __attribute__((ext_vector_type(4)));

#define DEVI static __device__ __forceinline__

static constexpr int Bn = 4, Cc = 192, Hh = 256, Wd = 256;
static constexpr int NHd = 6, HD = 32;
static constexpr int Mtot = Bn * Hh * Wd;          // 262144 pixels
static constexpr float EPSv = 1e-5f;
static constexpr float SCQ = 0.2550629072427404f;  // hd^-0.5 * log2(e), folded into Q

DEVI f32x4 mfma16(bf16x8 a, bf16x8 b, f32x4 c) {
    return __builtin_amdgcn_mfma_f32_16x16x32_bf16(a, b, c, 0, 0, 0);
}

DEVI f32x4 mfma16f8(long long a, long long b, f32x4 c) {
    return __builtin_amdgcn_mfma_f32_16x16x32_fp8_fp8(a, b, c, 0, 0, 0);
}

template <bool HIGH>
DEVI unsigned cvtpk_fp8(float lo, float hi, unsigned old) {
    return (unsigned)__builtin_amdgcn_cvt_pk_fp8_f32(lo, hi, (int)old, HIGH);
}

// ---------------------------------------------------------------- K0: weights
// WT576[n][k] bf16: rows 0..191 = Wq^T * SCQ, rows 192..575 = Wkv^T.
// WoT8[n][k] fp8 = Wo^T (for the fp8 O-projection).
__global__ __launch_bounds__(256) void k_prep(const float* Wq, const float* Wkv,
                                              const float* Wo, bf16* WT,
                                              unsigned char* WoT8) {
    int idx = blockIdx.x * 256 + threadIdx.x;
    if (idx < 576 * 192) {
        int n = idx / 192, k = idx % 192;
        float v = (n < 192) ? Wq[k * 192 + n] * SCQ : Wkv[k * 384 + (n - 192)];
        WT[idx] = (bf16)v;
    } else if (idx < 576 * 192 + 192 * 192) {
        int j = idx - 576 * 192;
        int n = j / 192, k = j % 192;
        float w = Wo[k * 192 + n];
        WoT8[j] = (unsigned char)(cvtpk_fp8<false>(w, w, 0u) & 0xFFu);
    }
}

// ---------------------------------------------------------------- K1: fused LN + QKV projection
// r18 structure: register-resident pass 1, A written once, nt-outer GEMM
// (W read once). Outputs fp8 planes QKV8[plane=n>>5][pix][32].
__global__ __launch_bounds__(256) void k_lnqkv(const float* __restrict__ x,
                                               const float* __restrict__ gamma,
                                               const float* __restrict__ beta,
                                               const bf16* __restrict__ WT,
                                               const float* __restrict__ bq,
                                               const float* __restrict__ bkv,
                                               unsigned char* __restrict__ QKV8) {
    constexpr int AS = 200;                       // A-tile stride
    __shared__ __align__(16) bf16 A[64 * AS];
    __shared__ float red[2][4][64];
    __shared__ float sg[Cc], sbv[Cc];

    int tid = threadIdx.x;
    int q = tid >> 6, p = tid & 63;
    int base = blockIdx.x * 64;
    int b = base >> 16;
    int hw = base & 65535;
    int h = hw >> 8, w0 = hw & 255;
    if (tid < Cc) { sg[tid] = gamma[tid]; sbv[tid] = beta[tid]; }

    // pass 1: all 48 channel loads in flight at once; stats from registers
    const float* xb = x + ((size_t)(b * Cc + q * 48) * Hh + h) * Wd + w0 + p;
    float xv[48];
#pragma unroll
    for (int i = 0; i < 48; ++i) xv[i] = xb[(size_t)i * Hh * Wd];
    float s = 0.f, s2 = 0.f;
#pragma unroll
    for (int i = 0; i < 48; ++i) { s += xv[i]; s2 += xv[i] * xv[i]; }
    red[0][q][p] = s; red[1][q][p] = s2;
    __syncthreads();
    float mu = (red[0][0][p] + red[0][1][p] + red[0][2][p] + red[0][3][p]) * (1.f / 192.f);
    float m2 = (red[1][0][p] + red[1][1][p] + red[1][2][p] + red[1][3][p]) * (1.f / 192.f);
    float rs = rsqrtf(m2 - mu * mu + EPSv);
    // normalize from registers, write A once
#pragma unroll
    for (int i0 = 0; i0 < 48; i0 += 8) {
        bf16x8 o;
#pragma unroll
        for (int j = 0; j < 8; ++j) {
            int c = q * 48 + i0 + j;
            o[j] = (bf16)((xv[i0 + j] - mu) * rs * sg[c] + sbv[c]);
        }
        *(bf16x8*)&A[p * AS + q * 48 + i0] = o;
    }
    __syncthreads();

    // GEMM: 4 waves x 144 cols; nt streamed OUTER (W read once), mt inner.
    int lane = tid & 63, l15 = lane & 15, g = lane >> 4;
    const bf16* Wbase = WT + (size_t)(q * 144 + l15) * Cc + g * 8;
#pragma unroll 1
    for (int nt = 0; nt < 9; ++nt) {
        f32x4 acc[4] = {};
        const bf16* wp = Wbase + (size_t)nt * 16 * Cc;
#pragma unroll
        for (int kk = 0; kk < 6; ++kk) {
            bf16x8 wb = *(const bf16x8*)(wp + kk * 32);
#pragma unroll
            for (int mt = 0; mt < 4; ++mt) {
                bf16x8 a = *(bf16x8*)&A[(mt * 16 + l15) * AS + kk * 32 + g * 8];
                acc[mt] = mfma16(wb, a, acc[mt]);   // D[n][pix]
            }
        }
        int n0 = q * 144 + nt * 16 + g * 4;         // 4-group never crosses plane
        const float* bsrc = (n0 < 192) ? (bq + n0) : (bkv + n0 - 192);
        f32x4 b4 = *(const f32x4*)bsrc;
        if (n0 < 192) b4 *= SCQ;                    // Q bias pre-scaled like Wq
        unsigned char* outp = QKV8 + (size_t)(n0 >> 5) * Mtot * HD + (n0 & 31);
#pragma unroll
        for (int mt = 0; mt < 4; ++mt) {
            unsigned pk = 0;
            pk = cvtpk_fp8<false>(acc[mt][0] + b4[0], acc[mt][1] + b4[1], pk);
            pk = cvtpk_fp8<true>(acc[mt][2] + b4[2], acc[mt][3] + b4[3], pk);
            *(unsigned*)(outp + (size_t)(base + mt * 16 + l15) * HD) = pk;
        }
    }
}

// ---------------------------------------------------------------- K2: attention
// 2 waves x 128 threads per (head, window); q-tiles A/B share the K stream.
// FULL fp8: Q,K,V,P,O all fp8. In-register P via shuffles; LDS = V^T only.
__global__ __launch_bounds__(128) void k_attn(const unsigned char* __restrict__ QKV8,
                                              const float* __restrict__ bkv,
                                              unsigned char* __restrict__ AO8) {
    constexpr int VS = 264;                        // VT row stride BYTES
    int bid = blockIdx.x;
    bid = (bid & 7) * 3072 + (bid >> 3);          // chunked XCD swizzle (24576 = 8*3072)
    int head = bid >> 12;                          // /4096
    int win = bid & 4095;
    int b = win >> 10, wloc = win & 1023;
    int h0 = ((wloc >> 5) << 3), w0 = ((wloc & 31) << 3);
    bool interior = (h0 != 0) && (h0 != Hh - 8) && (w0 != 0) && (w0 != Wd - 8);

    int tid = threadIdx.x, wave = tid >> 6, lane = tid & 63;
    int l15 = lane & 15, g = lane >> 4;

    const unsigned char* Qh = QKV8 + (size_t)head * Mtot * HD;
    const unsigned char* Kh = QKV8 + (size_t)(6 + head) * Mtot * HD;
    const unsigned char* Vh = QKV8 + (size_t)(12 + head) * Mtot * HD;
    unsigned char* Oh = AO8 + (size_t)head * Mtot * HD;
    long long p00 = (long long)(b * Hh + h0 - 4) * Wd + (w0 - 4);

    __shared__ __align__(16) unsigned char VT8[32 * VS];  // fp8 V^T [d][kv]

    // ---- stage V^T (two kv rows per thread), fp8
#pragma unroll
    for (int rr = 0; rr < 2; ++rr) {
        int r = tid + rr * 128;
        unsigned wv[8];
        if (interior) {
            const unsigned char* vr = Vh + (p00 + (r >> 4) * Wd + (r & 15)) * HD;
            u32x4 a0 = *(const u32x4*)(vr);
            u32x4 a1 = *(const u32x4*)(vr + 16);
#pragma unroll
            for (int w = 0; w < 4; ++w) { wv[w] = a0[w]; wv[w + 4] = a1[w]; }
        } else {
            int ph = h0 - 4 + (r >> 4), pw = w0 - 4 + (r & 15);
            bool ok = ((unsigned)ph < (unsigned)Hh) && ((unsigned)pw < (unsigned)Wd);
            long long pix = ok ? ((long long)(b * Hh + ph) * Wd + pw) : 0;
            const unsigned char* vr = Vh + pix * HD;
            u32x4 a0 = *(const u32x4*)(vr);
            u32x4 a1 = *(const u32x4*)(vr + 16);
            const float* vb = bkv + Cc + head * HD;
#pragma unroll
            for (int w = 0; w < 8; ++w) {
                unsigned bw = 0;
                bw = cvtpk_fp8<false>(vb[4 * w], vb[4 * w + 1], bw);
                bw = cvtpk_fp8<true>(vb[4 * w + 2], vb[4 * w + 3], bw);
                unsigned lw = (w < 4) ? a0[w] : a1[w - 4];
                wv[w] = ok ? lw : bw;
            }
        }
#pragma unroll
        for (int w = 0; w < 8; ++w) {
            unsigned word = wv[w];
            VT8[(4 * w + 0) * VS + r] = (unsigned char)(word);
            VT8[(4 * w + 1) * VS + r] = (unsigned char)(word >> 8);
            VT8[(4 * w + 2) * VS + r] = (unsigned char)(word >> 16);
            VT8[(4 * w + 3) * VS + r] = (unsigned char)(word >> 24);
        }
    }

    // ---- Q fragments (fp8, 8B each) for the wave's two q-tiles
    int qrA = wave * 32 + l15;
    int qrB = qrA + 16;
    size_t qpixA = (size_t)(b * Hh + h0 + (qrA >> 3)) * Wd + w0 + (qrA & 7);
    size_t qpixB = (size_t)(b * Hh + h0 + (qrB >> 3)) * Wd + w0 + (qrB & 7);
    long long aqA = *(const long long*)(Qh + qpixA * HD + g * 8);
    long long aqB = *(const long long*)(Qh + qpixB * HD + g * 8);
    __syncthreads();

    // ---- S^T = K @ Q^T (fp8) fused with exp/pack, 4 chunks of 4 kv-tiles.
    const f32x4 z = {0.f, 0.f, 0.f, 0.f};
    const unsigned char* kp = Kh + (p00 + l15) * HD + g * 8;
    float sa0 = 0.f, sa1 = 0.f, sa2 = 0.f, sa3 = 0.f;
    float sb0 = 0.f, sb1 = 0.f, sb2 = 0.f, sb3 = 0.f;
    unsigned pkA[16], pkB[16];
    long long kb = 0;
    bool colok = true;
    if (!interior) {
        unsigned kb0 = 0, kb1 = 0;
        const float* kbp = bkv + head * HD + g * 8;
        kb0 = cvtpk_fp8<false>(kbp[0], kbp[1], kb0);
        kb0 = cvtpk_fp8<true>(kbp[2], kbp[3], kb0);
        kb1 = cvtpk_fp8<false>(kbp[4], kbp[5], kb1);
        kb1 = cvtpk_fp8<true>(kbp[6], kbp[7], kb1);
        kb = (long long)(((unsigned long long)kb1 << 32) | kb0);
        colok = ((unsigned)(w0 - 4 + l15) < (unsigned)Wd);
    }
#pragma unroll 1
    for (int c = 0; c < 4; ++c) {
        f32x4 sA[4], sB[4];
        __builtin_amdgcn_s_setprio(1);
        if (interior) {
#pragma unroll
            for (int u = 0; u < 4; ++u) {
                long long kf = *(const long long*)(kp + (size_t)(c * 4 + u) * Wd * HD);
                sA[u] = mfma16f8(kf, aqA, z);
                sB[u] = mfma16f8(kf, aqB, z);
            }
        } else {
#pragma unroll
            for (int u = 0; u < 4; ++u) {
                int t = c * 4 + u;
                int ph = h0 - 4 + t;              // wave-uniform
                long long kf;
                if ((unsigned)ph < (unsigned)Hh) {
                    kf = *(const long long*)(kp + (size_t)t * Wd * HD);
                    kf = colok ? kf : kb;
                } else {
                    kf = kb;
                }
                sA[u] = mfma16f8(kf, aqA, z);
                sB[u] = mfma16f8(kf, aqB, z);
            }
        }
        __builtin_amdgcn_s_setprio(0);
#pragma unroll
        for (int u = 0; u < 4; ++u) {
            float a0 = __builtin_amdgcn_exp2f(sA[u][0]);
            float a1 = __builtin_amdgcn_exp2f(sA[u][1]);
            float a2 = __builtin_amdgcn_exp2f(sA[u][2]);
            float a3 = __builtin_amdgcn_exp2f(sA[u][3]);
            sa0 += a0; sa1 += a1; sa2 += a2; sa3 += a3;
            unsigned wA = 0;
            wA = cvtpk_fp8<false>(a0, a1, wA);
            wA = cvtpk_fp8<true>(a2, a3, wA);
            pkA[c * 4 + u] = wA;
            float b0 = __builtin_amdgcn_exp2f(sB[u][0]);
            float b1 = __builtin_amdgcn_exp2f(sB[u][1]);
            float b2 = __builtin_amdgcn_exp2f(sB[u][2]);
            float b3 = __builtin_amdgcn_exp2f(sB[u][3]);
            sb0 += b0; sb1 += b1; sb2 += b2; sb3 += b3;
            unsigned wB = 0;
            wB = cvtpk_fp8<false>(b0, b1, wB);
            wB = cvtpk_fp8<true>(b2, b3, wB);
            pkB[c * 4 + u] = wB;
        }
    }
    float sumA = (sa0 + sa1) + (sa2 + sa3);
    sumA += __shfl_xor(sumA, 16);
    sumA += __shfl_xor(sumA, 32);
    float invA = __builtin_amdgcn_rcpf(sumA);
    float sumB = (sb0 + sb1) + (sb2 + sb3);
    sumB += __shfl_xor(sumB, 16);
    sumB += __shfl_xor(sumB, 32);
    float invB = __builtin_amdgcn_rcpf(sumB);

    // ---- O = P @ V in fp8 per q-tile; MACRO keeps pkA/pkB register-resident.
    // O stored fp8 (coalesced 16B per 16-lane group).
    int srcA = l15 | ((2 * (g & 1)) << 4);
    int srcB = srcA + 16;
    bool ghi = (g >> 1) != 0;
#define PV_EPILOGUE(PK, INV, JT)                                                        \
    {                                                                                   \
        f32x4 o0 = z, o1 = z;                                                           \
        _Pragma("unroll")                                                               \
        for (int kk = 0; kk < 8; ++kk) {                                                \
            unsigned s0 = __shfl(PK[2 * kk], srcA);                                     \
            unsigned s1 = __shfl(PK[2 * kk + 1], srcA);                                 \
            unsigned s2 = __shfl(PK[2 * kk], srcB);                                     \
            unsigned s3 = __shfl(PK[2 * kk + 1], srcB);                                 \
            unsigned lo = ghi ? s1 : s0;                                                \
            unsigned hi = ghi ? s3 : s2;                                                \
            long long ap = (long long)(((unsigned long long)hi << 32) | lo);            \
            long long bv0 = *(const long long*)&VT8[l15 * VS + kk * 32 + g * 8];        \
            long long bv1 = *(const long long*)&VT8[(16 + l15) * VS + kk * 32 + g * 8]; \
            __builtin_amdgcn_s_setprio(1);                                              \
            o0 = mfma16f8(ap, bv0, o0);                                                 \
            o1 = mfma16f8(ap, bv1, o1);                                                 \
            __builtin_amdgcn_s_setprio(0);                                              \
        }                                                                               \
        float invr[4];                                                                  \
        _Pragma("unroll")                                                               \
        for (int r = 0; r < 4; ++r)                                                     \
            invr[r] = __shfl(INV, (lane & 48) | (g * 4 + r));                           \
        _Pragma("unroll")                                                               \
        for (int r = 0; r < 4; ++r) {                                                   \
            int row = wave * 32 + JT * 16 + g * 4 + r;                                  \
            size_t pix = (size_t)(b * Hh + h0 + (row >> 3)) * Wd + w0 + (row & 7);      \
            float v0 = o0[r] * invr[r];                                                 \
            float v1 = o1[r] * invr[r];                                                 \
            Oh[pix * HD + l15] = (unsigned char)(cvtpk_fp8<false>(v0, v0, 0u) & 0xFFu); \
            Oh[pix * HD + 16 + l15] = (unsigned char)(cvtpk_fp8<false>(v1, v1, 0u) & 0xFFu); \
        }                                                                               \
    }
    PV_EPILOGUE(pkA, invA, 0)
    PV_EPILOGUE(pkB, invB, 1)
#undef PV_EPILOGUE
}

// ---------------------------------------------------------------- K3: O-proj + residual (BHWC->BCHW)
// A is fp8 AO8[plane=c>>5][pix][32]; Wo fp8; GEMM via mfma16f8.
__global__ __launch_bounds__(256) void k_out(const unsigned char* __restrict__ AO8,
                                             const unsigned char* __restrict__ WoT8,
                                             const float* __restrict__ bo,
                                             const float* __restrict__ x,
                                             float* __restrict__ out) {
    int row0 = blockIdx.x * 64;
    int tid = threadIdx.x, wave = tid >> 6, lane = tid & 63;
    int l15 = lane & 15, g = lane >> 4;
    int nb = wave * 48;
    f32x4 acc[4][3] = {};
    const unsigned char* Arow[4];
#pragma unroll
    for (int mt = 0; mt < 4; ++mt) Arow[mt] = AO8 + (size_t)(row0 + mt * 16 + l15) * HD + g * 8;
    const unsigned char* Wrow[3];
#pragma unroll
    for (int nt = 0; nt < 3; ++nt) Wrow[nt] = WoT8 + (size_t)(nb + nt * 16 + l15) * Cc + g * 8;
#pragma unroll
    for (int kk = 0; kk < 6; ++kk) {
        long long a[4];
#pragma unroll
        for (int mt = 0; mt < 4; ++mt)
            a[mt] = *(const long long*)(Arow[mt] + (size_t)kk * Mtot * HD);
#pragma unroll
        for (int nt = 0; nt < 3; ++nt) {
            long long bb = *(const long long*)(Wrow[nt] + kk * 32);
#pragma unroll
            for (int mt = 0; mt < 4; ++mt) acc[mt][nt] = mfma16f8(a[mt], bb, acc[mt][nt]);
        }
    }
    __shared__ float st[192 * 65];
#pragma unroll
    for (int nt = 0; nt < 3; ++nt) {
        float bval = bo[nb + nt * 16 + l15];
#pragma unroll
        for (int mt = 0; mt < 4; ++mt)
#pragma unroll
            for (int r = 0; r < 4; ++r) {
                int ccol = nb + nt * 16 + l15;
                int px = mt * 16 + g * 4 + r;
                st[ccol * 65 + px] = acc[mt][nt][r] + bval;
            }
    }
    __syncthreads();
    int bb2 = row0 / (Hh * Wd);
    int rem = row0 % (Hh * Wd);
    int h = rem / Wd, wstart = rem % Wd;
    for (int idx = tid; idx < 192 * 64; idx += 256) {
        int cc = idx >> 6, px = idx & 63;
        size_t ga = ((size_t)(bb2 * Cc + cc) * Hh + h) * Wd + wstart + px;
        out[ga] = st[cc * 65 + px] + x[ga];
    }
}

// ---------------------------------------------------------------- launch
extern "C" void kernel_launch(void* const* d_in, const int* in_sizes, int n_in,
                              void* d_out, int out_size, void* d_ws, size_t ws_size,
                              hipStream_t stream) {
    const float* x     = (const float*)d_in[0];
    const float* gamma = (const float*)d_in[1];
    const float* beta  = (const float*)d_in[2];
    const float* Wq    = (const float*)d_in[3];
    const float* bq    = (const float*)d_in[4];
    const float* Wkv   = (const float*)d_in[5];
    const float* bkv   = (const float*)d_in[6];
    const float* Wo    = (const float*)d_in[7];
    const float* bo    = (const float*)d_in[8];
    float* out = (float*)d_out;

    char* ws = (char*)d_ws;
    constexpr size_t P8  = (size_t)Mtot * HD;               // 8388608 B (fp8 plane)
    constexpr size_t QKV8SZ = 18 * P8;                      // 150994944
    constexpr size_t AO8SZ  = 6 * P8;                       // 50331648
    unsigned char* QKV8 = (unsigned char*)(ws);
    unsigned char* AO8  = (unsigned char*)(ws + QKV8SZ);
    bf16*          WT   = (bf16*)(ws + QKV8SZ + AO8SZ);     // 221184 B
    unsigned char* WoT8 = (unsigned char*)(ws + QKV8SZ + AO8SZ + 221184); // 36864 B

    k_prep<<<576, 256, 0, stream>>>(Wq, Wkv, Wo, WT, WoT8);
    k_lnqkv<<<Mtot / 64, 256, 0, stream>>>(x, gamma, beta, WT, bq, bkv, QKV8);
    k_attn<<<4096 * NHd, 128, 0, stream>>>(QKV8, bkv, AO8);
    k_out<<<Mtot / 64, 256, 0, stream>>>(AO8, WoT8, bo, x, out);
}

// Round 21
// 380.043 us; speedup vs baseline: 1.1669x; 1.0616x over previous
//
#include <hip/hip_runtime.h>
#include <hip/hip_bf16.h>

typedef __bf16 bf16;
typedef __bf16 bf16x8 __attribute__((ext_vector_type(8)));
typedef float f32x4 __attribute__((ext_vector_type(4)));
typedef unsigned int u32x2 __attribute__((ext_vector_type(2)));
typedef unsigned int u32x4 __attribute__((ext_vector_type(4)));

#define DEVI static __device__ __forceinline__

static constexpr int Bn = 4, Cc = 192, Hh = 256, Wd = 256;
static constexpr int NHd = 6, HD = 32;
static constexpr int Mtot = Bn * Hh * Wd;          // 262144 pixels
static constexpr float EPSv = 1e-5f;
static constexpr float SCQ = 0.2550629072427404f;  // hd^-0.5 * log2(e), folded into Q

DEVI f32x4 mfma16f8(long long a, long long b, f32x4 c) {
    return __builtin_amdgcn_mfma_f32_16x16x32_fp8_fp8(a, b, c, 0, 0, 0);
}

template <bool HIGH>
DEVI unsigned cvtpk_fp8(float lo, float hi, unsigned old) {
    return (unsigned)__builtin_amdgcn_cvt_pk_fp8_f32(lo, hi, (int)old, HIGH);
}

// ---------------------------------------------------------------- K0: weights
// WT8[n][k] fp8: rows 0..191 = Wq^T*SCQ*16, rows 192..575 = Wkv^T*16
// (x16 keeps the small weights out of e4m3 subnormal range; epilogue /16).
// WoT8[n][k] fp8 = Wo^T.
__global__ __launch_bounds__(256) void k_prep(const float* Wq, const float* Wkv,
                                              const float* Wo, unsigned char* WT8,
                                              unsigned char* WoT8) {
    int idx = blockIdx.x * 256 + threadIdx.x;
    if (idx < 576 * 192) {
        int n = idx / 192, k = idx % 192;
        float v = (n < 192) ? Wq[k * 192 + n] * (SCQ * 16.f)
                            : Wkv[k * 384 + (n - 192)] * 16.f;
        WT8[idx] = (unsigned char)(cvtpk_fp8<false>(v, v, 0u) & 0xFFu);
    } else if (idx < 576 * 192 + 192 * 192) {
        int j = idx - 576 * 192;
        int n = j / 192, k = j % 192;
        float w = Wo[k * 192 + n];
        WoT8[j] = (unsigned char)(cvtpk_fp8<false>(w, w, 0u) & 0xFFu);
    }
}

// ---------------------------------------------------------------- K1: fused LN + QKV projection
// Block = one (b,h) row of 256 pixels; thread owns one pixel -> LN reduction
// is thread-local (no LDS reduce), x read in 1KB/channel chunks (pass 2
// re-read is L2-hot). A-tile fp8 in LDS; fp8x fp8 GEMM, W frags held in regs
// (loaded once per nt), acc[4] streamed. Outputs fp8 planes.
__global__ __launch_bounds__(256) void k_lnqkv(const float* __restrict__ x,
                                               const float* __restrict__ gamma,
                                               const float* __restrict__ beta,
                                               const unsigned char* __restrict__ WT8,
                                               const float* __restrict__ bq,
                                               const float* __restrict__ bkv,
                                               unsigned char* __restrict__ QKV8) {
    constexpr int AS = 200;                       // fp8 A stride (bytes); 50 words -> conflict-free b64
    __shared__ __align__(16) unsigned char A[256 * AS];   // 51.2 KB

    int tid = threadIdx.x;
    int bid = blockIdx.x;
    int b = bid >> 8, h = bid & 255;
    const size_t cs = (size_t)Hh * Wd;
    const float* xb = x + ((size_t)(b * Cc) * Hh + h) * Wd + tid;

    // pass 1: thread-local stats over 192 channels (1KB/channel per block)
    float s0 = 0.f, s1 = 0.f, q0 = 0.f, q1 = 0.f;
#pragma unroll 8
    for (int c = 0; c < Cc; c += 2) {
        float v0 = xb[(size_t)c * cs], v1 = xb[(size_t)(c + 1) * cs];
        s0 += v0; q0 += v0 * v0;
        s1 += v1; q1 += v1 * v1;
    }
    float mu = (s0 + s1) * (1.f / 192.f);
    float m2 = (q0 + q1) * (1.f / 192.f);
    float rs = rsqrtf(m2 - mu * mu + EPSv);

    // pass 2: re-read (L2-hot), normalize, fp8-pack into LDS
#pragma unroll 4
    for (int c = 0; c < Cc; c += 4) {
        float v0 = (xb[(size_t)(c + 0) * cs] - mu) * rs * gamma[c + 0] + beta[c + 0];
        float v1 = (xb[(size_t)(c + 1) * cs] - mu) * rs * gamma[c + 1] + beta[c + 1];
        float v2 = (xb[(size_t)(c + 2) * cs] - mu) * rs * gamma[c + 2] + beta[c + 2];
        float v3 = (xb[(size_t)(c + 3) * cs] - mu) * rs * gamma[c + 3] + beta[c + 3];
        unsigned pk = 0;
        pk = cvtpk_fp8<false>(v0, v1, pk);
        pk = cvtpk_fp8<true>(v2, v3, pk);
        *(unsigned*)&A[tid * AS + c] = pk;
    }
    __syncthreads();

    // GEMM fp8: wave q -> 144 output cols; W frags once per nt; acc[4] streamed
    int q = tid >> 6, lane = tid & 63, l15 = lane & 15, g = lane >> 4;
    const unsigned char* Wbase = WT8 + (size_t)(q * 144 + l15) * Cc + g * 8;
    size_t pixrow = ((size_t)(b * Hh) + h) * Wd;
#pragma unroll 1
    for (int nt = 0; nt < 9; ++nt) {
        long long wf[6];
        const unsigned char* wp = Wbase + (size_t)nt * 16 * Cc;
#pragma unroll
        for (int kk = 0; kk < 6; ++kk) wf[kk] = *(const long long*)(wp + kk * 32);
        int n0 = q * 144 + nt * 16 + g * 4;         // 4-group never crosses plane
        const float* bsrc = (n0 < 192) ? (bq + n0) : (bkv + n0 - 192);
        f32x4 b4 = *(const f32x4*)bsrc;
        if (n0 < 192) b4 *= SCQ;                    // Q bias pre-scaled like Wq
        unsigned char* outp = QKV8 + (size_t)(n0 >> 5) * Mtot * HD + (n0 & 31);
#pragma unroll 1
        for (int mtg = 0; mtg < 4; ++mtg) {
            f32x4 acc[4] = {};
#pragma unroll
            for (int kk = 0; kk < 6; ++kk) {
#pragma unroll
                for (int m4 = 0; m4 < 4; ++m4) {
                    int px = (mtg * 4 + m4) * 16 + l15;
                    long long a = *(const long long*)&A[px * AS + kk * 32 + g * 8];
                    acc[m4] = mfma16f8(wf[kk], a, acc[m4]);   // D[n][pix]
                }
            }
#pragma unroll
            for (int m4 = 0; m4 < 4; ++m4) {
                int px = (mtg * 4 + m4) * 16 + l15;
                unsigned pk = 0;
                pk = cvtpk_fp8<false>(fmaf(acc[m4][0], 0.0625f, b4[0]),
                                      fmaf(acc[m4][1], 0.0625f, b4[1]), pk);
                pk = cvtpk_fp8<true>(fmaf(acc[m4][2], 0.0625f, b4[2]),
                                     fmaf(acc[m4][3], 0.0625f, b4[3]), pk);
                *(unsigned*)(outp + (pixrow + px) * HD) = pk;
            }
        }
    }
}

// ---------------------------------------------------------------- K2: attention
// 2 waves x 128 threads per (head, window); q-tiles A/B share the K stream.
// FULL fp8: Q,K,V,P,O all fp8. In-register P via shuffles; LDS = V^T only.
__global__ __launch_bounds__(128) void k_attn(const unsigned char* __restrict__ QKV8,
                                              const float* __restrict__ bkv,
                                              unsigned char* __restrict__ AO8) {
    constexpr int VS = 264;                        // VT row stride BYTES
    int bid = blockIdx.x;
    bid = (bid & 7) * 3072 + (bid >> 3);          // chunked XCD swizzle (24576 = 8*3072)
    int head = bid >> 12;                          // /4096
    int win = bid & 4095;
    int b = win >> 10, wloc = win & 1023;
    int h0 = ((wloc >> 5) << 3), w0 = ((wloc & 31) << 3);
    bool interior = (h0 != 0) && (h0 != Hh - 8) && (w0 != 0) && (w0 != Wd - 8);

    int tid = threadIdx.x, wave = tid >> 6, lane = tid & 63;
    int l15 = lane & 15, g = lane >> 4;

    const unsigned char* Qh = QKV8 + (size_t)head * Mtot * HD;
    const unsigned char* Kh = QKV8 + (size_t)(6 + head) * Mtot * HD;
    const unsigned char* Vh = QKV8 + (size_t)(12 + head) * Mtot * HD;
    unsigned char* Oh = AO8 + (size_t)head * Mtot * HD;
    long long p00 = (long long)(b * Hh + h0 - 4) * Wd + (w0 - 4);

    __shared__ __align__(16) unsigned char VT8[32 * VS];  // fp8 V^T [d][kv]

    // ---- stage V^T (two kv rows per thread), fp8
#pragma unroll
    for (int rr = 0; rr < 2; ++rr) {
        int r = tid + rr * 128;
        unsigned wv[8];
        if (interior) {
            const unsigned char* vr = Vh + (p00 + (r >> 4) * Wd + (r & 15)) * HD;
            u32x4 a0 = *(const u32x4*)(vr);
            u32x4 a1 = *(const u32x4*)(vr + 16);
#pragma unroll
            for (int w = 0; w < 4; ++w) { wv[w] = a0[w]; wv[w + 4] = a1[w]; }
        } else {
            int ph = h0 - 4 + (r >> 4), pw = w0 - 4 + (r & 15);
            bool ok = ((unsigned)ph < (unsigned)Hh) && ((unsigned)pw < (unsigned)Wd);
            long long pix = ok ? ((long long)(b * Hh + ph) * Wd + pw) : 0;
            const unsigned char* vr = Vh + pix * HD;
            u32x4 a0 = *(const u32x4*)(vr);
            u32x4 a1 = *(const u32x4*)(vr + 16);
            const float* vb = bkv + Cc + head * HD;
#pragma unroll
            for (int w = 0; w < 8; ++w) {
                unsigned bw = 0;
                bw = cvtpk_fp8<false>(vb[4 * w], vb[4 * w + 1], bw);
                bw = cvtpk_fp8<true>(vb[4 * w + 2], vb[4 * w + 3], bw);
                unsigned lw = (w < 4) ? a0[w] : a1[w - 4];
                wv[w] = ok ? lw : bw;
            }
        }
#pragma unroll
        for (int w = 0; w < 8; ++w) {
            unsigned word = wv[w];
            VT8[(4 * w + 0) * VS + r] = (unsigned char)(word);
            VT8[(4 * w + 1) * VS + r] = (unsigned char)(word >> 8);
            VT8[(4 * w + 2) * VS + r] = (unsigned char)(word >> 16);
            VT8[(4 * w + 3) * VS + r] = (unsigned char)(word >> 24);
        }
    }

    // ---- Q fragments (fp8, 8B each) for the wave's two q-tiles
    int qrA = wave * 32 + l15;
    int qrB = qrA + 16;
    size_t qpixA = (size_t)(b * Hh + h0 + (qrA >> 3)) * Wd + w0 + (qrA & 7);
    size_t qpixB = (size_t)(b * Hh + h0 + (qrB >> 3)) * Wd + w0 + (qrB & 7);
    long long aqA = *(const long long*)(Qh + qpixA * HD + g * 8);
    long long aqB = *(const long long*)(Qh + qpixB * HD + g * 8);
    __syncthreads();

    // ---- S^T = K @ Q^T (fp8) fused with exp/pack, 4 chunks of 4 kv-tiles.
    const f32x4 z = {0.f, 0.f, 0.f, 0.f};
    const unsigned char* kp = Kh + (p00 + l15) * HD + g * 8;
    float sa0 = 0.f, sa1 = 0.f, sa2 = 0.f, sa3 = 0.f;
    float sb0 = 0.f, sb1 = 0.f, sb2 = 0.f, sb3 = 0.f;
    unsigned pkA[16], pkB[16];
    long long kb = 0;
    bool colok = true;
    if (!interior) {
        unsigned kb0 = 0, kb1 = 0;
        const float* kbp = bkv + head * HD + g * 8;
        kb0 = cvtpk_fp8<false>(kbp[0], kbp[1], kb0);
        kb0 = cvtpk_fp8<true>(kbp[2], kbp[3], kb0);
        kb1 = cvtpk_fp8<false>(kbp[4], kbp[5], kb1);
        kb1 = cvtpk_fp8<true>(kbp[6], kbp[7], kb1);
        kb = (long long)(((unsigned long long)kb1 << 32) | kb0);
        colok = ((unsigned)(w0 - 4 + l15) < (unsigned)Wd);
    }
#pragma unroll 1
    for (int c = 0; c < 4; ++c) {
        f32x4 sA[4], sB[4];
        __builtin_amdgcn_s_setprio(1);
        if (interior) {
#pragma unroll
            for (int u = 0; u < 4; ++u) {
                long long kf = *(const long long*)(kp + (size_t)(c * 4 + u) * Wd * HD);
                sA[u] = mfma16f8(kf, aqA, z);
                sB[u] = mfma16f8(kf, aqB, z);
            }
        } else {
#pragma unroll
            for (int u = 0; u < 4; ++u) {
                int t = c * 4 + u;
                int ph = h0 - 4 + t;              // wave-uniform
                long long kf;
                if ((unsigned)ph < (unsigned)Hh) {
                    kf = *(const long long*)(kp + (size_t)t * Wd * HD);
                    kf = colok ? kf : kb;
                } else {
                    kf = kb;
                }
                sA[u] = mfma16f8(kf, aqA, z);
                sB[u] = mfma16f8(kf, aqB, z);
            }
        }
        __builtin_amdgcn_s_setprio(0);
#pragma unroll
        for (int u = 0; u < 4; ++u) {
            float a0 = __builtin_amdgcn_exp2f(sA[u][0]);
            float a1 = __builtin_amdgcn_exp2f(sA[u][1]);
            float a2 = __builtin_amdgcn_exp2f(sA[u][2]);
            float a3 = __builtin_amdgcn_exp2f(sA[u][3]);
            sa0 += a0; sa1 += a1; sa2 += a2; sa3 += a3;
            unsigned wA = 0;
            wA = cvtpk_fp8<false>(a0, a1, wA);
            wA = cvtpk_fp8<true>(a2, a3, wA);
            pkA[c * 4 + u] = wA;
            float b0 = __builtin_amdgcn_exp2f(sB[u][0]);
            float b1 = __builtin_amdgcn_exp2f(sB[u][1]);
            float b2 = __builtin_amdgcn_exp2f(sB[u][2]);
            float b3 = __builtin_amdgcn_exp2f(sB[u][3]);
            sb0 += b0; sb1 += b1; sb2 += b2; sb3 += b3;
            unsigned wB = 0;
            wB = cvtpk_fp8<false>(b0, b1, wB);
            wB = cvtpk_fp8<true>(b2, b3, wB);
            pkB[c * 4 + u] = wB;
        }
    }
    float sumA = (sa0 + sa1) + (sa2 + sa3);
    sumA += __shfl_xor(sumA, 16);
    sumA += __shfl_xor(sumA, 32);
    float invA = __builtin_amdgcn_rcpf(sumA);
    float sumB = (sb0 + sb1) + (sb2 + sb3);
    sumB += __shfl_xor(sumB, 16);
    sumB += __shfl_xor(sumB, 32);
    float invB = __builtin_amdgcn_rcpf(sumB);

    // ---- O = P @ V in fp8 per q-tile; MACRO keeps pkA/pkB register-resident.
    int srcA = l15 | ((2 * (g & 1)) << 4);
    int srcB = srcA + 16;
    bool ghi = (g >> 1) != 0;
#define PV_EPILOGUE(PK, INV, JT)                                                        \
    {                                                                                   \
        f32x4 o0 = z, o1 = z;                                                           \
        _Pragma("unroll")                                                               \
        for (int kk = 0; kk < 8; ++kk) {                                                \
            unsigned s0 = __shfl(PK[2 * kk], srcA);                                     \
            unsigned s1 = __shfl(PK[2 * kk + 1], srcA);                                 \
            unsigned s2 = __shfl(PK[2 * kk], srcB);                                     \
            unsigned s3 = __shfl(PK[2 * kk + 1], srcB);                                 \
            unsigned lo = ghi ? s1 : s0;                                                \
            unsigned hi = ghi ? s3 : s2;                                                \
            long long ap = (long long)(((unsigned long long)hi << 32) | lo);            \
            long long bv0 = *(const long long*)&VT8[l15 * VS + kk * 32 + g * 8];        \
            long long bv1 = *(const long long*)&VT8[(16 + l15) * VS + kk * 32 + g * 8]; \
            __builtin_amdgcn_s_setprio(1);                                              \
            o0 = mfma16f8(ap, bv0, o0);                                                 \
            o1 = mfma16f8(ap, bv1, o1);                                                 \
            __builtin_amdgcn_s_setprio(0);                                              \
        }                                                                               \
        float invr[4];                                                                  \
        _Pragma("unroll")                                                               \
        for (int r = 0; r < 4; ++r)                                                     \
            invr[r] = __shfl(INV, (lane & 48) | (g * 4 + r));                           \
        _Pragma("unroll")                                                               \
        for (int r = 0; r < 4; ++r) {                                                   \
            int row = wave * 32 + JT * 16 + g * 4 + r;                                  \
            size_t pix = (size_t)(b * Hh + h0 + (row >> 3)) * Wd + w0 + (row & 7);      \
            float v0 = o0[r] * invr[r];                                                 \
            float v1 = o1[r] * invr[r];                                                 \
            Oh[pix * HD + l15] = (unsigned char)(cvtpk_fp8<false>(v0, v0, 0u) & 0xFFu); \
            Oh[pix * HD + 16 + l15] = (unsigned char)(cvtpk_fp8<false>(v1, v1, 0u) & 0xFFu); \
        }                                                                               \
    }
    PV_EPILOGUE(pkA, invA, 0)
    PV_EPILOGUE(pkB, invB, 1)
#undef PV_EPILOGUE
}

// ---------------------------------------------------------------- K3: O-proj + residual (BHWC->BCHW)
// A is fp8 AO8[plane=c>>5][pix][32]; Wo fp8; GEMM via mfma16f8.
__global__ __launch_bounds__(256) void k_out(const unsigned char* __restrict__ AO8,
                                             const unsigned char* __restrict__ WoT8,
                                             const float* __restrict__ bo,
                                             const float* __restrict__ x,
                                             float* __restrict__ out) {
    int row0 = blockIdx.x * 64;
    int tid = threadIdx.x, wave = tid >> 6, lane = tid & 63;
    int l15 = lane & 15, g = lane >> 4;
    int nb = wave * 48;
    f32x4 acc[4][3] = {};
    const unsigned char* Arow[4];
#pragma unroll
    for (int mt = 0; mt < 4; ++mt) Arow[mt] = AO8 + (size_t)(row0 + mt * 16 + l15) * HD + g * 8;
    const unsigned char* Wrow[3];
#pragma unroll
    for (int nt = 0; nt < 3; ++nt) Wrow[nt] = WoT8 + (size_t)(nb + nt * 16 + l15) * Cc + g * 8;
#pragma unroll
    for (int kk = 0; kk < 6; ++kk) {
        long long a[4];
#pragma unroll
        for (int mt = 0; mt < 4; ++mt)
            a[mt] = *(const long long*)(Arow[mt] + (size_t)kk * Mtot * HD);
#pragma unroll
        for (int nt = 0; nt < 3; ++nt) {
            long long bb = *(const long long*)(Wrow[nt] + kk * 32);
#pragma unroll
            for (int mt = 0; mt < 4; ++mt) acc[mt][nt] = mfma16f8(a[mt], bb, acc[mt][nt]);
        }
    }
    __shared__ float st[192 * 65];
#pragma unroll
    for (int nt = 0; nt < 3; ++nt) {
        float bval = bo[nb + nt * 16 + l15];
#pragma unroll
        for (int mt = 0; mt < 4; ++mt)
#pragma unroll
            for (int r = 0; r < 4; ++r) {
                int ccol = nb + nt * 16 + l15;
                int px = mt * 16 + g * 4 + r;
                st[ccol * 65 + px] = acc[mt][nt][r] + bval;
            }
    }
    __syncthreads();
    int bb2 = row0 / (Hh * Wd);
    int rem = row0 % (Hh * Wd);
    int h = rem / Wd, wstart = rem % Wd;
    for (int idx = tid; idx < 192 * 64; idx += 256) {
        int cc = idx >> 6, px = idx & 63;
        size_t ga = ((size_t)(bb2 * Cc + cc) * Hh + h) * Wd + wstart + px;
        out[ga] = st[cc * 65 + px] + x[ga];
    }
}

// ---------------------------------------------------------------- launch
extern "C" void kernel_launch(void* const* d_in, const int* in_sizes, int n_in,
                              void* d_out, int out_size, void* d_ws, size_t ws_size,
                              hipStream_t stream) {
    const float* x     = (const float*)d_in[0];
    const float* gamma = (const float*)d_in[1];
    const float* beta  = (const float*)d_in[2];
    const float* Wq    = (const float*)d_in[3];
    const float* bq    = (const float*)d_in[4];
    const float* Wkv   = (const float*)d_in[5];
    const float* bkv   = (const float*)d_in[6];
    const float* Wo    = (const float*)d_in[7];
    const float* bo    = (const float*)d_in[8];
    float* out = (float*)d_out;

    char* ws = (char*)d_ws;
    constexpr size_t P8  = (size_t)Mtot * HD;               // 8388608 B (fp8 plane)
    constexpr size_t QKV8SZ = 18 * P8;                      // 150994944
    constexpr size_t AO8SZ  = 6 * P8;                       // 50331648
    unsigned char* QKV8 = (unsigned char*)(ws);
    unsigned char* AO8  = (unsigned char*)(ws + QKV8SZ);
    unsigned char* WT8  = (unsigned char*)(ws + QKV8SZ + AO8SZ);           // 110592 B
    unsigned char* WoT8 = (unsigned char*)(ws + QKV8SZ + AO8SZ + 110592);  // 36864 B

    k_prep<<<576, 256, 0, stream>>>(Wq, Wkv, Wo, WT8, WoT8);
    k_lnqkv<<<Mtot / 256, 256, 0, stream>>>(x, gamma, beta, WT8, bq, bkv, QKV8);
    k_attn<<<4096 * NHd, 128, 0, stream>>>(QKV8, bkv, AO8);
    k_out<<<Mtot / 64, 256, 0, stream>>>(AO8, WoT8, bo, x, out);
}

// Round 22
// 346.704 us; speedup vs baseline: 1.2791x; 1.0962x over previous
//
#include <hip/hip_runtime.h>
#include <hip/hip_bf16.h>

typedef __bf16 bf16;
typedef float f32x2 __attribute__((ext_vector_type(2)));
typedef float f32x4 __attribute__((ext_vector_type(4)));
typedef unsigned int u32x2 __attribute__((ext_vector_type(2)));
typedef unsigned int u32x4 __attribute__((ext_vector_type(4)));

#define DEVI static __device__ __forceinline__

static constexpr int Bn = 4, Cc = 192, Hh = 256, Wd = 256;
static constexpr int NHd = 6, HD = 32;
static constexpr int Mtot = Bn * Hh * Wd;          // 262144 pixels
static constexpr float EPSv = 1e-5f;
static constexpr float SCQ = 0.2550629072427404f;  // hd^-0.5 * log2(e), folded into Q

DEVI f32x4 mfma16f8(long long a, long long b, f32x4 c) {
    return __builtin_amdgcn_mfma_f32_16x16x32_fp8_fp8(a, b, c, 0, 0, 0);
}

template <bool HIGH>
DEVI unsigned cvtpk_fp8(float lo, float hi, unsigned old) {
    return (unsigned)__builtin_amdgcn_cvt_pk_fp8_f32(lo, hi, (int)old, HIGH);
}

template <bool HIGH>
DEVI f32x2 cvtpk_f32_fp8(unsigned w) {
    return __builtin_amdgcn_cvt_pk_f32_fp8((int)w, HIGH);
}

// ---------------------------------------------------------------- K0: weights
// WT8[n][k] fp8: rows 0..191 = Wq^T*SCQ*16, rows 192..575 = Wkv^T*16
// (x16 keeps the small weights out of e4m3 subnormal range; epilogue /16).
// WoT8[n][k] fp8 = Wo^T.
__global__ __launch_bounds__(256) void k_prep(const float* Wq, const float* Wkv,
                                              const float* Wo, unsigned char* WT8,
                                              unsigned char* WoT8) {
    int idx = blockIdx.x * 256 + threadIdx.x;
    if (idx < 576 * 192) {
        int n = idx / 192, k = idx % 192;
        float v = (n < 192) ? Wq[k * 192 + n] * (SCQ * 16.f)
                            : Wkv[k * 384 + (n - 192)] * 16.f;
        WT8[idx] = (unsigned char)(cvtpk_fp8<false>(v, v, 0u) & 0xFFu);
    } else if (idx < 576 * 192 + 192 * 192) {
        int j = idx - 576 * 192;
        int n = j / 192, k = j % 192;
        float w = Wo[k * 192 + n];
        WoT8[j] = (unsigned char)(cvtpk_fp8<false>(w, w, 0u) & 0xFFu);
    }
}

// ---------------------------------------------------------------- K1: fused LN + QKV projection
// Block = one (b,h) row of 256 pixels; thread owns one pixel. x read ONCE:
// pass 1 packs raw x to fp8 in LDS while accumulating f32 stats; pass 2
// normalizes IN LDS (cvt_pk_f32_fp8 -> fma -> repack). fp8 GEMM as r21.
__global__ __launch_bounds__(256) void k_lnqkv(const float* __restrict__ x,
                                               const float* __restrict__ gamma,
                                               const float* __restrict__ beta,
                                               const unsigned char* __restrict__ WT8,
                                               const float* __restrict__ bq,
                                               const float* __restrict__ bkv,
                                               unsigned char* __restrict__ QKV8) {
    constexpr int AS = 200;                       // fp8 A stride (bytes); 50 words -> conflict-free b64
    __shared__ __align__(16) unsigned char A[256 * AS];   // 51.2 KB

    int tid = threadIdx.x;
    int bid = blockIdx.x;
    int b = bid >> 8, h = bid & 255;
    const size_t cs = (size_t)Hh * Wd;
    const float* xb = x + ((size_t)(b * Cc) * Hh + h) * Wd + tid;

    // pass 1: single x read; f32 stats + raw fp8 stash into LDS
    float s0 = 0.f, s1 = 0.f, q0 = 0.f, q1 = 0.f;
#pragma unroll 4
    for (int c = 0; c < Cc; c += 4) {
        float v0 = xb[(size_t)(c + 0) * cs], v1 = xb[(size_t)(c + 1) * cs];
        float v2 = xb[(size_t)(c + 2) * cs], v3 = xb[(size_t)(c + 3) * cs];
        s0 += v0 + v2; q0 += v0 * v0 + v2 * v2;
        s1 += v1 + v3; q1 += v1 * v1 + v3 * v3;
        unsigned pk = 0;
        pk = cvtpk_fp8<false>(v0, v1, pk);
        pk = cvtpk_fp8<true>(v2, v3, pk);
        *(unsigned*)&A[tid * AS + c] = pk;
    }
    float mu = (s0 + s1) * (1.f / 192.f);
    float m2 = (q0 + q1) * (1.f / 192.f);
    float rs = rsqrtf(m2 - mu * mu + EPSv);

    // pass 2: normalize in LDS (thread-local region; no barrier needed yet)
#pragma unroll 4
    for (int c = 0; c < Cc; c += 4) {
        unsigned a = *(unsigned*)&A[tid * AS + c];
        f32x2 lo = cvtpk_f32_fp8<false>(a);
        f32x2 hi = cvtpk_f32_fp8<true>(a);
        float v0 = (lo[0] - mu) * rs * gamma[c + 0] + beta[c + 0];
        float v1 = (lo[1] - mu) * rs * gamma[c + 1] + beta[c + 1];
        float v2 = (hi[0] - mu) * rs * gamma[c + 2] + beta[c + 2];
        float v3 = (hi[1] - mu) * rs * gamma[c + 3] + beta[c + 3];
        unsigned pk = 0;
        pk = cvtpk_fp8<false>(v0, v1, pk);
        pk = cvtpk_fp8<true>(v2, v3, pk);
        *(unsigned*)&A[tid * AS + c] = pk;
    }
    __syncthreads();

    // GEMM fp8: wave q -> 144 output cols; W frags once per nt; acc[4] streamed
    int q = tid >> 6, lane = tid & 63, l15 = lane & 15, g = lane >> 4;
    const unsigned char* Wbase = WT8 + (size_t)(q * 144 + l15) * Cc + g * 8;
    size_t pixrow = ((size_t)(b * Hh) + h) * Wd;
#pragma unroll 1
    for (int nt = 0; nt < 9; ++nt) {
        long long wf[6];
        const unsigned char* wp = Wbase + (size_t)nt * 16 * Cc;
#pragma unroll
        for (int kk = 0; kk < 6; ++kk) wf[kk] = *(const long long*)(wp + kk * 32);
        int n0 = q * 144 + nt * 16 + g * 4;         // 4-group never crosses plane
        const float* bsrc = (n0 < 192) ? (bq + n0) : (bkv + n0 - 192);
        f32x4 b4 = *(const f32x4*)bsrc;
        if (n0 < 192) b4 *= SCQ;                    // Q bias pre-scaled like Wq
        unsigned char* outp = QKV8 + (size_t)(n0 >> 5) * Mtot * HD + (n0 & 31);
#pragma unroll 1
        for (int mtg = 0; mtg < 4; ++mtg) {
            f32x4 acc[4] = {};
#pragma unroll
            for (int kk = 0; kk < 6; ++kk) {
#pragma unroll
                for (int m4 = 0; m4 < 4; ++m4) {
                    int px = (mtg * 4 + m4) * 16 + l15;
                    long long a = *(const long long*)&A[px * AS + kk * 32 + g * 8];
                    acc[m4] = mfma16f8(wf[kk], a, acc[m4]);   // D[n][pix]
                }
            }
#pragma unroll
            for (int m4 = 0; m4 < 4; ++m4) {
                int px = (mtg * 4 + m4) * 16 + l15;
                unsigned pk = 0;
                pk = cvtpk_fp8<false>(fmaf(acc[m4][0], 0.0625f, b4[0]),
                                      fmaf(acc[m4][1], 0.0625f, b4[1]), pk);
                pk = cvtpk_fp8<true>(fmaf(acc[m4][2], 0.0625f, b4[2]),
                                     fmaf(acc[m4][3], 0.0625f, b4[3]), pk);
                *(unsigned*)(outp + (pixrow + px) * HD) = pk;
            }
        }
    }
}

// ---------------------------------------------------------------- K2: attention
// 2 waves x 128 threads per (head, window); q-tiles A/B share the K stream.
// FULL fp8: Q,K,V,P,O all fp8. In-register P via shuffles; LDS = V^T only.
__global__ __launch_bounds__(128) void k_attn(const unsigned char* __restrict__ QKV8,
                                              const float* __restrict__ bkv,
                                              unsigned char* __restrict__ AO8) {
    constexpr int VS = 264;                        // VT row stride BYTES
    int bid = blockIdx.x;
    bid = (bid & 7) * 3072 + (bid >> 3);          // chunked XCD swizzle (24576 = 8*3072)
    int head = bid >> 12;                          // /4096
    int win = bid & 4095;
    int b = win >> 10, wloc = win & 1023;
    int h0 = ((wloc >> 5) << 3), w0 = ((wloc & 31) << 3);
    bool interior = (h0 != 0) && (h0 != Hh - 8) && (w0 != 0) && (w0 != Wd - 8);

    int tid = threadIdx.x, wave = tid >> 6, lane = tid & 63;
    int l15 = lane & 15, g = lane >> 4;

    const unsigned char* Qh = QKV8 + (size_t)head * Mtot * HD;
    const unsigned char* Kh = QKV8 + (size_t)(6 + head) * Mtot * HD;
    const unsigned char* Vh = QKV8 + (size_t)(12 + head) * Mtot * HD;
    unsigned char* Oh = AO8 + (size_t)head * Mtot * HD;
    long long p00 = (long long)(b * Hh + h0 - 4) * Wd + (w0 - 4);

    __shared__ __align__(16) unsigned char VT8[32 * VS];  // fp8 V^T [d][kv]

    // ---- stage V^T (two kv rows per thread), fp8
#pragma unroll
    for (int rr = 0; rr < 2; ++rr) {
        int r = tid + rr * 128;
        unsigned wv[8];
        if (interior) {
            const unsigned char* vr = Vh + (p00 + (r >> 4) * Wd + (r & 15)) * HD;
            u32x4 a0 = *(const u32x4*)(vr);
            u32x4 a1 = *(const u32x4*)(vr + 16);
#pragma unroll
            for (int w = 0; w < 4; ++w) { wv[w] = a0[w]; wv[w + 4] = a1[w]; }
        } else {
            int ph = h0 - 4 + (r >> 4), pw = w0 - 4 + (r & 15);
            bool ok = ((unsigned)ph < (unsigned)Hh) && ((unsigned)pw < (unsigned)Wd);
            long long pix = ok ? ((long long)(b * Hh + ph) * Wd + pw) : 0;
            const unsigned char* vr = Vh + pix * HD;
            u32x4 a0 = *(const u32x4*)(vr);
            u32x4 a1 = *(const u32x4*)(vr + 16);
            const float* vb = bkv + Cc + head * HD;
#pragma unroll
            for (int w = 0; w < 8; ++w) {
                unsigned bw = 0;
                bw = cvtpk_fp8<false>(vb[4 * w], vb[4 * w + 1], bw);
                bw = cvtpk_fp8<true>(vb[4 * w + 2], vb[4 * w + 3], bw);
                unsigned lw = (w < 4) ? a0[w] : a1[w - 4];
                wv[w] = ok ? lw : bw;
            }
        }
#pragma unroll
        for (int w = 0; w < 8; ++w) {
            unsigned word = wv[w];
            VT8[(4 * w + 0) * VS + r] = (unsigned char)(word);
            VT8[(4 * w + 1) * VS + r] = (unsigned char)(word >> 8);
            VT8[(4 * w + 2) * VS + r] = (unsigned char)(word >> 16);
            VT8[(4 * w + 3) * VS + r] = (unsigned char)(word >> 24);
        }
    }

    // ---- Q fragments (fp8, 8B each) for the wave's two q-tiles
    int qrA = wave * 32 + l15;
    int qrB = qrA + 16;
    size_t qpixA = (size_t)(b * Hh + h0 + (qrA >> 3)) * Wd + w0 + (qrA & 7);
    size_t qpixB = (size_t)(b * Hh + h0 + (qrB >> 3)) * Wd + w0 + (qrB & 7);
    long long aqA = *(const long long*)(Qh + qpixA * HD + g * 8);
    long long aqB = *(const long long*)(Qh + qpixB * HD + g * 8);
    __syncthreads();

    // ---- S^T = K @ Q^T (fp8) fused with exp/pack, 4 chunks of 4 kv-tiles.
    const f32x4 z = {0.f, 0.f, 0.f, 0.f};
    const unsigned char* kp = Kh + (p00 + l15) * HD + g * 8;
    float sa0 = 0.f, sa1 = 0.f, sa2 = 0.f, sa3 = 0.f;
    float sb0 = 0.f, sb1 = 0.f, sb2 = 0.f, sb3 = 0.f;
    unsigned pkA[16], pkB[16];
    long long kb = 0;
    bool colok = true;
    if (!interior) {
        unsigned kb0 = 0, kb1 = 0;
        const float* kbp = bkv + head * HD + g * 8;
        kb0 = cvtpk_fp8<false>(kbp[0], kbp[1], kb0);
        kb0 = cvtpk_fp8<true>(kbp[2], kbp[3], kb0);
        kb1 = cvtpk_fp8<false>(kbp[4], kbp[5], kb1);
        kb1 = cvtpk_fp8<true>(kbp[6], kbp[7], kb1);
        kb = (long long)(((unsigned long long)kb1 << 32) | kb0);
        colok = ((unsigned)(w0 - 4 + l15) < (unsigned)Wd);
    }
#pragma unroll 1
    for (int c = 0; c < 4; ++c) {
        f32x4 sA[4], sB[4];
        __builtin_amdgcn_s_setprio(1);
        if (interior) {
#pragma unroll
            for (int u = 0; u < 4; ++u) {
                long long kf = *(const long long*)(kp + (size_t)(c * 4 + u) * Wd * HD);
                sA[u] = mfma16f8(kf, aqA, z);
                sB[u] = mfma16f8(kf, aqB, z);
            }
        } else {
#pragma unroll
            for (int u = 0; u < 4; ++u) {
                int t = c * 4 + u;
                int ph = h0 - 4 + t;              // wave-uniform
                long long kf;
                if ((unsigned)ph < (unsigned)Hh) {
                    kf = *(const long long*)(kp + (size_t)t * Wd * HD);
                    kf = colok ? kf : kb;
                } else {
                    kf = kb;
                }
                sA[u] = mfma16f8(kf, aqA, z);
                sB[u] = mfma16f8(kf, aqB, z);
            }
        }
        __builtin_amdgcn_s_setprio(0);
#pragma unroll
        for (int u = 0; u < 4; ++u) {
            float a0 = __builtin_amdgcn_exp2f(sA[u][0]);
            float a1 = __builtin_amdgcn_exp2f(sA[u][1]);
            float a2 = __builtin_amdgcn_exp2f(sA[u][2]);
            float a3 = __builtin_amdgcn_exp2f(sA[u][3]);
            sa0 += a0; sa1 += a1; sa2 += a2; sa3 += a3;
            unsigned wA = 0;
            wA = cvtpk_fp8<false>(a0, a1, wA);
            wA = cvtpk_fp8<true>(a2, a3, wA);
            pkA[c * 4 + u] = wA;
            float b0 = __builtin_amdgcn_exp2f(sB[u][0]);
            float b1 = __builtin_amdgcn_exp2f(sB[u][1]);
            float b2 = __builtin_amdgcn_exp2f(sB[u][2]);
            float b3 = __builtin_amdgcn_exp2f(sB[u][3]);
            sb0 += b0; sb1 += b1; sb2 += b2; sb3 += b3;
            unsigned wB = 0;
            wB = cvtpk_fp8<false>(b0, b1, wB);
            wB = cvtpk_fp8<true>(b2, b3, wB);
            pkB[c * 4 + u] = wB;
        }
    }
    float sumA = (sa0 + sa1) + (sa2 + sa3);
    sumA += __shfl_xor(sumA, 16);
    sumA += __shfl_xor(sumA, 32);
    float invA = __builtin_amdgcn_rcpf(sumA);
    float sumB = (sb0 + sb1) + (sb2 + sb3);
    sumB += __shfl_xor(sumB, 16);
    sumB += __shfl_xor(sumB, 32);
    float invB = __builtin_amdgcn_rcpf(sumB);

    // ---- O = P @ V in fp8 per q-tile; MACRO keeps pkA/pkB register-resident.
    int srcA = l15 | ((2 * (g & 1)) << 4);
    int srcB = srcA + 16;
    bool ghi = (g >> 1) != 0;
#define PV_EPILOGUE(PK, INV, JT)                                                        \
    {                                                                                   \
        f32x4 o0 = z, o1 = z;                                                           \
        _Pragma("unroll")                                                               \
        for (int kk = 0; kk < 8; ++kk) {                                                \
            unsigned s0 = __shfl(PK[2 * kk], srcA);                                     \
            unsigned s1 = __shfl(PK[2 * kk + 1], srcA);                                 \
            unsigned s2 = __shfl(PK[2 * kk], srcB);                                     \
            unsigned s3 = __shfl(PK[2 * kk + 1], srcB);                                 \
            unsigned lo = ghi ? s1 : s0;                                                \
            unsigned hi = ghi ? s3 : s2;                                                \
            long long ap = (long long)(((unsigned long long)hi << 32) | lo);            \
            long long bv0 = *(const long long*)&VT8[l15 * VS + kk * 32 + g * 8];        \
            long long bv1 = *(const long long*)&VT8[(16 + l15) * VS + kk * 32 + g * 8]; \
            __builtin_amdgcn_s_setprio(1);                                              \
            o0 = mfma16f8(ap, bv0, o0);                                                 \
            o1 = mfma16f8(ap, bv1, o1);                                                 \
            __builtin_amdgcn_s_setprio(0);                                              \
        }                                                                               \
        float invr[4];                                                                  \
        _Pragma("unroll")                                                               \
        for (int r = 0; r < 4; ++r)                                                     \
            invr[r] = __shfl(INV, (lane & 48) | (g * 4 + r));                           \
        _Pragma("unroll")                                                               \
        for (int r = 0; r < 4; ++r) {                                                   \
            int row = wave * 32 + JT * 16 + g * 4 + r;                                  \
            size_t pix = (size_t)(b * Hh + h0 + (row >> 3)) * Wd + w0 + (row & 7);      \
            float v0 = o0[r] * invr[r];                                                 \
            float v1 = o1[r] * invr[r];                                                 \
            Oh[pix * HD + l15] = (unsigned char)(cvtpk_fp8<false>(v0, v0, 0u) & 0xFFu); \
            Oh[pix * HD + 16 + l15] = (unsigned char)(cvtpk_fp8<false>(v1, v1, 0u) & 0xFFu); \
        }                                                                               \
    }
    PV_EPILOGUE(pkA, invA, 0)
    PV_EPILOGUE(pkB, invB, 1)
#undef PV_EPILOGUE
}

// ---------------------------------------------------------------- K3: O-proj + residual (BHWC->BCHW)
// A is fp8 AO8[plane=c>>5][pix][32]; Wo fp8; GEMM via mfma16f8.
__global__ __launch_bounds__(256) void k_out(const unsigned char* __restrict__ AO8,
                                             const unsigned char* __restrict__ WoT8,
                                             const float* __restrict__ bo,
                                             const float* __restrict__ x,
                                             float* __restrict__ out) {
    int row0 = blockIdx.x * 64;
    int tid = threadIdx.x, wave = tid >> 6, lane = tid & 63;
    int l15 = lane & 15, g = lane >> 4;
    int nb = wave * 48;
    f32x4 acc[4][3] = {};
    const unsigned char* Arow[4];
#pragma unroll
    for (int mt = 0; mt < 4; ++mt) Arow[mt] = AO8 + (size_t)(row0 + mt * 16 + l15) * HD + g * 8;
    const unsigned char* Wrow[3];
#pragma unroll
    for (int nt = 0; nt < 3; ++nt) Wrow[nt] = WoT8 + (size_t)(nb + nt * 16 + l15) * Cc + g * 8;
#pragma unroll
    for (int kk = 0; kk < 6; ++kk) {
        long long a[4];
#pragma unroll
        for (int mt = 0; mt < 4; ++mt)
            a[mt] = *(const long long*)(Arow[mt] + (size_t)kk * Mtot * HD);
#pragma unroll
        for (int nt = 0; nt < 3; ++nt) {
            long long bb = *(const long long*)(Wrow[nt] + kk * 32);
#pragma unroll
            for (int mt = 0; mt < 4; ++mt) acc[mt][nt] = mfma16f8(a[mt], bb, acc[mt][nt]);
        }
    }
    __shared__ float st[192 * 65];
#pragma unroll
    for (int nt = 0; nt < 3; ++nt) {
        float bval = bo[nb + nt * 16 + l15];
#pragma unroll
        for (int mt = 0; mt < 4; ++mt)
#pragma unroll
            for (int r = 0; r < 4; ++r) {
                int ccol = nb + nt * 16 + l15;
                int px = mt * 16 + g * 4 + r;
                st[ccol * 65 + px] = acc[mt][nt][r] + bval;
            }
    }
    __syncthreads();
    int bb2 = row0 / (Hh * Wd);
    int rem = row0 % (Hh * Wd);
    int h = rem / Wd, wstart = rem % Wd;
    for (int idx = tid; idx < 192 * 64; idx += 256) {
        int cc = idx >> 6, px = idx & 63;
        size_t ga = ((size_t)(bb2 * Cc + cc) * Hh + h) * Wd + wstart + px;
        out[ga] = st[cc * 65 + px] + x[ga];
    }
}

// ---------------------------------------------------------------- launch
extern "C" void kernel_launch(void* const* d_in, const int* in_sizes, int n_in,
                              void* d_out, int out_size, void* d_ws, size_t ws_size,
                              hipStream_t stream) {
    const float* x     = (const float*)d_in[0];
    const float* gamma = (const float*)d_in[1];
    const float* beta  = (const float*)d_in[2];
    const float* Wq    = (const float*)d_in[3];
    const float* bq    = (const float*)d_in[4];
    const float* Wkv   = (const float*)d_in[5];
    const float* bkv   = (const float*)d_in[6];
    const float* Wo    = (const float*)d_in[7];
    const float* bo    = (const float*)d_in[8];
    float* out = (float*)d_out;

    char* ws = (char*)d_ws;
    constexpr size_t P8  = (size_t)Mtot * HD;               // 8388608 B (fp8 plane)
    constexpr size_t QKV8SZ = 18 * P8;                      // 150994944
    constexpr size_t AO8SZ  = 6 * P8;                       // 50331648
    unsigned char* QKV8 = (unsigned char*)(ws);
    unsigned char* AO8  = (unsigned char*)(ws + QKV8SZ);
    unsigned char* WT8  = (unsigned char*)(ws + QKV8SZ + AO8SZ);           // 110592 B
    unsigned char* WoT8 = (unsigned char*)(ws + QKV8SZ + AO8SZ + 110592);  // 36864 B

    k_prep<<<576, 256, 0, stream>>>(Wq, Wkv, Wo, WT8, WoT8);
    k_lnqkv<<<Mtot / 256, 256, 0, stream>>>(x, gamma, beta, WT8, bq, bkv, QKV8);
    k_attn<<<4096 * NHd, 128, 0, stream>>>(QKV8, bkv, AO8);
    k_out<<<Mtot / 64, 256, 0, stream>>>(AO8, WoT8, bo, x, out);
}